// Round 9
// baseline (131.387 us; speedup 1.0000x reference)
//
#include <hip/hip_runtime.h>
#include <stdint.h>

#define NN 8192
#define CC 128
#define TT 512
#define LL 30
#define CAP 64

typedef unsigned int uint32;
typedef unsigned long long ull;
typedef unsigned short u16;

typedef float f32x4 __attribute__((ext_vector_type(4)));
typedef short bf16x8 __attribute__((ext_vector_type(8)));

#define STAT_SCALE 1048576.0f
#define STAT_INV (1.0f / 1048576.0f)

__device__ __forceinline__ float bf2f(uint32 h) { return __uint_as_float(h << 16); }
__device__ __forceinline__ u16 f2bf(float f) {
    uint32 u = __float_as_uint(f);
    u = (u + 0x7fffu + ((u >> 16) & 1u)) >> 16;
    return (u16)u;
}
__device__ __forceinline__ uint32 pack2(float a, float b) {
    return (uint32)f2bf(a) | ((uint32)f2bf(b) << 16);
}
// coef from int64 stats: a = g*rsqrt(var+eps), b = be - mu*a
__device__ __forceinline__ void coef_from_stats(const ull* __restrict__ st, int c,
                                                const float* __restrict__ g,
                                                const float* __restrict__ be,
                                                float& ca, float& cb) {
    float s = (float)(long long)st[c] * STAT_INV;
    float q = (float)(long long)st[128 + c] * STAT_INV;
    float mu = s * (1.f / NN);
    float var = q * (1.f / NN) - mu * mu;
    float rs = rsqrtf(var + 1e-5f);
    ca = g[c] * rs;
    cb = be[c] - mu * ca;
}

// ============ k_pre: adj scan + fused layer-1 agg (from f32 x) + W pack + init ============
// blocks [0,2048): adj rows (scan + agg1); [2048,2336): wfrag; 2336: init
__global__ __launch_bounds__(256) void k_pre(
    const float* __restrict__ adj,
    const float* __restrict__ W1r, const float* __restrict__ W1s,
    const float* __restrict__ W2r, const float* __restrict__ W2s,
    const float* __restrict__ W3r, const float* __restrict__ W3s,
    const float* __restrict__ Wl, const float* __restrict__ x0,
    int* __restrict__ nbr, int* __restrict__ cnt,
    u16* __restrict__ wfrag,
    u16* __restrict__ yp1, u16* __restrict__ yp2, u16* __restrict__ yp3,
    u16* __restrict__ Abraw, ull* __restrict__ statsAcc) {
    int b = blockIdx.x, tid = threadIdx.x;
    if (b < 2048) {
        int row = b * 4 + (tid >> 6);
        int lane = tid & 63;
        const float4* arow = (const float4*)(adj + (size_t)row * NN);
        int base = 0;
        int* dst = nbr + (size_t)row * CAP;
        for (int it = 0; it < 32; ++it) {
            float4 v = arow[it * 64 + lane];
            float vv[4] = {v.x, v.y, v.z, v.w};
#pragma unroll
            for (int j = 0; j < 4; ++j) {
                unsigned long long m = __ballot(vv[j] != 0.f);
                if (vv[j] != 0.f) {
                    int pos = base + __popcll(m & ((1ull << lane) - 1ull));
                    if (pos < CAP) dst[pos] = it * 256 + lane * 4 + j;
                }
                base += __popcll(m);
            }
        }
        int nn = base < CAP ? base : CAP;
        int npad = (nn + 3) & ~3;
        for (int p = nn + lane; p < npad; p += 64) dst[p] = NN;  // sentinel
        if (lane == 0) cnt[row] = nn;
        // fused layer-1 aggregation straight from f32 x (L2/L3-resident)
        int c = lane * 2;
        float a0 = 0.f, a1 = 0.f;
        for (int j = 0; j < npad; j += 4) {
            int4 m = *(const int4*)(dst + j);
            if (m.x < NN) { float2 v = *(const float2*)(x0 + (size_t)m.x * CC + c); a0 += v.x; a1 += v.y; }
            if (m.y < NN) { float2 v = *(const float2*)(x0 + (size_t)m.y * CC + c); a0 += v.x; a1 += v.y; }
            if (m.z < NN) { float2 v = *(const float2*)(x0 + (size_t)m.z * CC + c); a0 += v.x; a1 += v.y; }
            if (m.w < NN) { float2 v = *(const float2*)(x0 + (size_t)m.w * CC + c); a0 += v.x; a1 += v.y; }
        }
        *(uint32*)(Abraw + (size_t)row * CC + c) = pack2(a0, a1);
    } else if (b < 2336) {
        int bb = b - 2048;
        const float* Wa;
        const float* Wb;
        int tile, gbase;
        if (bb < 64)       { Wa = W1r; Wb = W1s; tile = bb;       gbase = 0; }
        else if (bb < 128) { Wa = W2r; Wb = W2s; tile = bb - 64;  gbase = 64; }
        else if (bb < 192) { Wa = W3r; Wb = W3s; tile = bb - 128; gbase = 128; }
        else               { Wa = Wl;  Wb = nullptr; tile = bb - 192; gbase = 192; }
        int kt = tile >> 3, nt = tile & 7;
        int lane = tid & 63, i0 = (tid >> 6) * 2;
        int n = nt * 16 + (lane & 15);
        u16* dst = wfrag + ((size_t)(gbase + tile) * 64 + lane) * 8;
#pragma unroll
        for (int ii = 0; ii < 2; ++ii) {
            int i = i0 + ii;
            int k = kt * 32 + ((lane >> 4) * 8) + i;
            float v;
            if (Wb) v = (k < 128) ? Wa[k * CC + n] : Wb[(k - 128) * CC + n];
            else    v = Wa[k * CC + n];
            dst[i] = f2bf(v);
        }
    } else {
        if (tid < 128) {
            yp1[(size_t)NN * CC + tid] = 0;   // sentinel zero rows
            yp2[(size_t)NN * CC + tid] = 0;
            yp3[(size_t)NN * CC + tid] = 0;
#pragma unroll
            for (int l = 0; l < 3; ++l) {     // zero int64 stats accumulators
                statsAcc[l * 256 + tid] = 0ull;
                statsAcc[l * 256 + 128 + tid] = 0ull;
            }
        }
    }
}

// ============ k_agg: Abraw[row] = sum_nbr(src) (raw bf16) ============
__global__ __launch_bounds__(256) void k_agg(const u16* __restrict__ src,
                                             const int* __restrict__ nbr,
                                             const int* __restrict__ cnt,
                                             u16* __restrict__ Abraw) {
    int row = blockIdx.x * 4 + (threadIdx.x >> 6);
    int lane = threadIdx.x & 63;
    int c = lane * 2;
    int nreal = cnt[row];
    int npad = (nreal + 3) & ~3;
    const int* nb = nbr + (size_t)row * CAP;
    float a0 = 0.f, a1 = 0.f;
    for (int j = 0; j < npad; j += 4) {
        int4 m = *(const int4*)(nb + j);
        uint32 v0 = *(const uint32*)(src + (size_t)m.x * CC + c);
        uint32 v1 = *(const uint32*)(src + (size_t)m.y * CC + c);
        uint32 v2 = *(const uint32*)(src + (size_t)m.z * CC + c);
        uint32 v3 = *(const uint32*)(src + (size_t)m.w * CC + c);
        a0 += bf2f(v0 & 0xffffu); a1 += bf2f(v0 >> 16);
        a0 += bf2f(v1 & 0xffffu); a1 += bf2f(v1 >> 16);
        a0 += bf2f(v2 & 0xffffu); a1 += bf2f(v2 >> 16);
        a0 += bf2f(v3 & 0xffffu); a1 += bf2f(v3 >> 16);
    }
    *(uint32*)(Abraw + (size_t)row * CC + c) = pack2(a0, a1);
}

// ============ k_gemm<LAYER>: stage A, yp = relu(A@[Wr;Ws]+bias), int64 stats atomics ============
// 256 blocks x 512 threads (8 waves): wave w -> rows (w>>2)*16, cols (w&3)*32. (R5 geometry)
template <int LAYER>
__global__ __launch_bounds__(512) void k_gemm(const u16* __restrict__ Abraw,
                                              const float* __restrict__ x0,
                                              const u16* __restrict__ yprev,
                                              const int* __restrict__ cnt,
                                              const u16* __restrict__ wfrag,
                                              const float* __restrict__ bias,
                                              const ull* __restrict__ statsPrev,
                                              const float* __restrict__ g,
                                              const float* __restrict__ be,
                                              ull* __restrict__ statsOut,
                                              u16* __restrict__ yp) {
    __shared__ u16 A[32][264];  // +8 pad
    __shared__ float sSum[CC], sSq[CC];
    __shared__ alignas(16) float cA[CC];
    __shared__ alignas(16) float cB[CC];
    int tid = threadIdx.x, lane = tid & 63, wid = tid >> 6;
    int row0 = blockIdx.x * 32;
    if (tid < CC) {
        sSum[tid] = 0.f; sSq[tid] = 0.f;
        if constexpr (LAYER > 1) {
            float a, b;
            coef_from_stats(statsPrev, tid, g, be, a, b);
            cA[tid] = a; cB[tid] = b;
        }
    }
    __syncthreads();
    for (int i = tid; i < 1024; i += 512) {
        int r = i >> 5, k = (i & 31) * 8;
        int row = row0 + r;
        uint4 o;
        if constexpr (LAYER == 1) {
            if (k < 128) {
                o = *(const uint4*)(Abraw + (size_t)row * CC + k);
            } else {
                int c = k - 128;
                float4 v0 = *(const float4*)(x0 + (size_t)row * CC + c);
                float4 v1 = *(const float4*)(x0 + (size_t)row * CC + c + 4);
                o.x = pack2(v0.x, v0.y); o.y = pack2(v0.z, v0.w);
                o.z = pack2(v1.x, v1.y); o.w = pack2(v1.z, v1.w);
            }
        } else {
            uint4 raw;
            float fn;
            int c;
            if (k < 128) {
                c = k;
                raw = *(const uint4*)(Abraw + (size_t)row * CC + k);
                fn = (float)cnt[row];
            } else {
                c = k - 128;
                raw = *(const uint4*)(yprev + (size_t)row * CC + c);
                fn = 1.f;
            }
            float4 a0 = *(const float4*)(cA + c);
            float4 a1 = *(const float4*)(cA + c + 4);
            float4 b0 = *(const float4*)(cB + c);
            float4 b1 = *(const float4*)(cB + c + 4);
            o.x = pack2(a0.x * bf2f(raw.x & 0xffffu) + b0.x * fn, a0.y * bf2f(raw.x >> 16) + b0.y * fn);
            o.y = pack2(a0.z * bf2f(raw.y & 0xffffu) + b0.z * fn, a0.w * bf2f(raw.y >> 16) + b0.w * fn);
            o.z = pack2(a1.x * bf2f(raw.z & 0xffffu) + b1.x * fn, a1.y * bf2f(raw.z >> 16) + b1.y * fn);
            o.w = pack2(a1.z * bf2f(raw.w & 0xffffu) + b1.z * fn, a1.w * bf2f(raw.w >> 16) + b1.w * fn);
        }
        *(uint4*)&A[r][k] = o;
    }
    __syncthreads();

    int mh = wid >> 2, nh = wid & 3;
    int arow = mh * 16 + (lane & 15);
    int kg = (lane >> 4) * 8;
    f32x4 acc[2];
#pragma unroll
    for (int nt = 0; nt < 2; ++nt) acc[nt] = (f32x4){0.f, 0.f, 0.f, 0.f};
#pragma unroll
    for (int kt = 0; kt < 8; ++kt) {
        bf16x8 a = *(const bf16x8*)&A[arow][kt * 32 + kg];
        const u16* wb = wfrag + ((size_t)(kt * 8 + nh * 2) * 64 + lane) * 8;
#pragma unroll
        for (int nt = 0; nt < 2; ++nt) {
            bf16x8 bfr = *(const bf16x8*)(wb + (size_t)nt * 512);
            acc[nt] = __builtin_amdgcn_mfma_f32_16x16x32_bf16(a, bfr, acc[nt], 0, 0, 0);
        }
    }
    int rowb = row0 + mh * 16 + ((lane >> 4) * 4);
#pragma unroll
    for (int nt = 0; nt < 2; ++nt) {
        int col = nh * 32 + nt * 16 + (lane & 15);
        float bv = bias[col];
        float s1 = 0.f, s2 = 0.f;
#pragma unroll
        for (int q = 0; q < 4; ++q) {
            float y = acc[nt][q] + bv;
            y = y > 0.f ? y : 0.f;
            yp[(size_t)(rowb + q) * CC + col] = f2bf(y);
            s1 += y;
            s2 += y * y;
        }
        s1 += __shfl_xor(s1, 16); s1 += __shfl_xor(s1, 32);
        s2 += __shfl_xor(s2, 16); s2 += __shfl_xor(s2, 32);
        if ((lane >> 4) == 0) { atomicAdd(&sSum[col], s1); atomicAdd(&sSq[col], s2); }
    }
    __syncthreads();
    // int64 fixed-point global accumulation: exact, commutative, deterministic
    if (tid < 128) {
        atomicAdd(statsOut + tid, (ull)(long long)llrintf(sSum[tid] * STAT_SCALE));
    } else if (tid < 256) {
        atomicAdd(statsOut + tid, (ull)(long long)llrintf(sSq[tid - 128] * STAT_SCALE));
    }
}

// ============ k_out: s-GEMM [0,512) + team [512,1024) + xcat normalize [1024,4096) ============
__global__ __launch_bounds__(256) void k_out(
    const u16* __restrict__ yp1, const u16* __restrict__ yp2, const u16* __restrict__ yp3,
    const ull* __restrict__ statsAcc,  // [3][256]
    const float* __restrict__ g1, const float* __restrict__ be1,
    const float* __restrict__ g2, const float* __restrict__ be2,
    const float* __restrict__ g3, const float* __restrict__ be3,
    const u16* __restrict__ wfL, const float* __restrict__ bias,
    const int* __restrict__ teams, const int* __restrict__ slen_p,
    const float* __restrict__ att,
    float* __restrict__ sout, float* __restrict__ xcat,
    float* __restrict__ oT, float* __restrict__ oS, float* __restrict__ oR) {
    __shared__ alignas(16) char pool[12544];   // s-gemm A tile / team scratch
    __shared__ alignas(16) float cAll[768];    // {a[128],b[128]} x 3 layers
    int b = blockIdx.x, tid = threadIdx.x;
    if (tid < 128) {
        const float* gs[3] = {g1, g2, g3};
        const float* bes[3] = {be1, be2, be3};
#pragma unroll
        for (int l = 0; l < 3; ++l) {
            float a, bb;
            coef_from_stats(statsAcc + l * 256, tid, gs[l], bes[l], a, bb);
            cAll[l * 256 + tid] = a;
            cAll[l * 256 + 128 + tid] = bb;
        }
    }
    __syncthreads();
    const u16* yps[3] = {yp1, yp2, yp3};
    if (b < 512) {
        u16 (*A)[392] = (u16(*)[392])pool;  // 16 x 392 = 12544B
        int lane = tid & 63, wid = tid >> 6;
        int row0 = b * 16;
        for (int i = tid; i < 768; i += 256) {
            int r = i / 48, kk = (i % 48) * 8;
            int seg = kk >> 7, c = kk & 127;
            uint4 raw = *(const uint4*)(yps[seg] + (size_t)(row0 + r) * CC + c);
            const float* cf = cAll + seg * 256;
            float4 av0 = *(const float4*)(cf + c);
            float4 av1 = *(const float4*)(cf + c + 4);
            float4 bv0 = *(const float4*)(cf + 128 + c);
            float4 bv1 = *(const float4*)(cf + 128 + c + 4);
            uint4 o;
            o.x = pack2(av0.x * bf2f(raw.x & 0xffffu) + bv0.x, av0.y * bf2f(raw.x >> 16) + bv0.y);
            o.y = pack2(av0.z * bf2f(raw.y & 0xffffu) + bv0.z, av0.w * bf2f(raw.y >> 16) + bv0.w);
            o.z = pack2(av1.x * bf2f(raw.z & 0xffffu) + bv1.x, av1.y * bf2f(raw.z >> 16) + bv1.y);
            o.w = pack2(av1.z * bf2f(raw.w & 0xffffu) + bv1.z, av1.w * bf2f(raw.w >> 16) + bv1.w);
            *(uint4*)&A[r][kk] = o;
        }
        __syncthreads();
        int nh = wid;
        int arow = lane & 15;
        int kg = (lane >> 4) * 8;
        f32x4 acc[2];
#pragma unroll
        for (int nt = 0; nt < 2; ++nt) acc[nt] = (f32x4){0.f, 0.f, 0.f, 0.f};
#pragma unroll
        for (int kt = 0; kt < 12; ++kt) {
            bf16x8 a = *(const bf16x8*)&A[arow][kt * 32 + kg];
            const u16* wb = wfL + ((size_t)(kt * 8 + nh * 2) * 64 + lane) * 8;
#pragma unroll
            for (int nt = 0; nt < 2; ++nt) {
                bf16x8 bfr = *(const bf16x8*)(wb + (size_t)nt * 512);
                acc[nt] = __builtin_amdgcn_mfma_f32_16x16x32_bf16(a, bfr, acc[nt], 0, 0, 0);
            }
        }
        int rowb = row0 + ((lane >> 4) * 4);
#pragma unroll
        for (int nt = 0; nt < 2; ++nt) {
            int col = nh * 32 + nt * 16 + (lane & 15);
            float bv = bias[col];
#pragma unroll
            for (int q = 0; q < 4; ++q) {
                float y = acc[nt][q] + bv;
                sout[(size_t)(rowb + q) * CC + col] = y > 0.f ? y : 0.f;
            }
        }
    } else if (b < 1024) {
        float* wT = (float*)pool;
        float* wS = wT + 32;
        float* wR = wS + 32;
        int* ids = (int*)(wR + 32);
        int t = b - 512;
        if (tid < 64) {
            int lane = tid;
            bool act = lane < LL;
            float a = act ? att[t * LL + lane] : 0.f;
            int id = act ? teams[t * LL + lane] : NN;
            if (act) ids[lane] = id;
            int sl = *slen_p;
            const float NEG = -1e30f;
            float v = act ? a : NEG;
#pragma unroll
            for (int o = 32; o > 0; o >>= 1) v = fmaxf(v, __shfl_xor(v, o));
            float mT = v;
            float eT = act ? __expf(a - mT) : 0.f;
            v = eT;
#pragma unroll
            for (int o = 32; o > 0; o >>= 1) v += __shfl_xor(v, o);
            float sT = v;
            bool inS = act && (lane < sl);
            v = inS ? a : NEG;
#pragma unroll
            for (int o = 32; o > 0; o >>= 1) v = fmaxf(v, __shfl_xor(v, o));
            float mS = v;
            float eS = inS ? __expf(a - mS) : 0.f;
            v = eS;
#pragma unroll
            for (int o = 32; o > 0; o >>= 1) v += __shfl_xor(v, o);
            float sS = v;
            bool inR = act && (lane >= sl) && (id != NN);
            v = inR ? a : NEG;
#pragma unroll
            for (int o = 32; o > 0; o >>= 1) v = fmaxf(v, __shfl_xor(v, o));
            float mR = v;
            float eR = inR ? __expf(a - mR) : 0.f;
            v = eR;
#pragma unroll
            for (int o = 32; o > 0; o >>= 1) v += __shfl_xor(v, o);
            float sR = v;
            if (act) {
                wT[lane] = eT / sT;
                wS[lane] = eS / sS;
                wR[lane] = eR / sR;
            }
        }
        __syncthreads();
        for (int d = tid; d < 384; d += 256) {
            int seg = d >> 7, c = d & 127;
            const u16* xb = yps[seg];
            float ca = cAll[seg * 256 + c];
            float cb = cAll[seg * 256 + 128 + c];
            float aT = 0.f, aS = 0.f, aR = 0.f;
            for (int l = 0; l < LL; ++l) {
                int id = ids[l];
                if (id < NN) {
                    float vv = ca * bf2f((uint32)xb[(size_t)id * CC + c]) + cb;
                    aT += wT[l] * vv;
                    aS += wS[l] * vv;
                    aR += wR[l] * vv;
                }
            }
            oT[(size_t)t * 384 + d] = aT;
            oS[(size_t)t * 384 + d] = aS;
            oR[(size_t)t * 384 + d] = aR;
        }
    } else {
        int idx = (b - 1024) * 256 + tid;  // one per 4 f32
        int n = idx / 96;
        int k = (idx % 96) * 4;
        int seg = k >> 7, c = k & 127;
        ushort4 raw = *(const ushort4*)(yps[seg] + (size_t)n * CC + c);
        const float* cf = cAll + seg * 256;
        float4 a = *(const float4*)(cf + c);
        float4 bb = *(const float4*)(cf + 128 + c);
        float4 o;
        o.x = a.x * bf2f((uint32)raw.x) + bb.x;
        o.y = a.y * bf2f((uint32)raw.y) + bb.y;
        o.z = a.z * bf2f((uint32)raw.z) + bb.z;
        o.w = a.w * bf2f((uint32)raw.w) + bb.w;
        *(float4*)(xcat + (size_t)n * 384 + k) = o;
    }
}

extern "C" void kernel_launch(void* const* d_in, const int* in_sizes, int n_in,
                              void* d_out, int out_size, void* d_ws, size_t ws_size,
                              hipStream_t stream) {
    const float* x = (const float*)d_in[0];
    const float* adj = (const float*)d_in[1];
    const int* teams = (const int*)d_in[2];
    const int* slen = (const int*)d_in[3];
    const float* W1r = (const float*)d_in[4];
    const float* b1 = (const float*)d_in[5];
    const float* W1s = (const float*)d_in[6];
    const float* W2r = (const float*)d_in[7];
    const float* b2 = (const float*)d_in[8];
    const float* W2s = (const float*)d_in[9];
    const float* W3r = (const float*)d_in[10];
    const float* b3 = (const float*)d_in[11];
    const float* W3s = (const float*)d_in[12];
    const float* g1 = (const float*)d_in[13];
    const float* be1 = (const float*)d_in[14];
    const float* g2 = (const float*)d_in[15];
    const float* be2 = (const float*)d_in[16];
    const float* g3 = (const float*)d_in[17];
    const float* be3 = (const float*)d_in[18];
    const float* Wl = (const float*)d_in[19];
    const float* bl = (const float*)d_in[20];
    const float* att = (const float*)d_in[21];

    float* out = (float*)d_out;
    float* s_out = out;
    float* xcat = out + (size_t)NN * CC;
    float* oT = xcat + (size_t)NN * 384;
    float* oS = oT + (size_t)TT * 384;
    float* oR = oS + (size_t)TT * 384;

    char* ws = (char*)d_ws;
    size_t off = 0;
    int* nbr = (int*)(ws + off); off += (size_t)NN * CAP * 4;
    int* cnt = (int*)(ws + off); off += (size_t)NN * 4;
    u16* yp1 = (u16*)(ws + off); off += (size_t)(NN + 1) * CC * 2;
    u16* yp2 = (u16*)(ws + off); off += (size_t)(NN + 1) * CC * 2;
    u16* yp3 = (u16*)(ws + off); off += (size_t)(NN + 1) * CC * 2;
    u16* Abraw = (u16*)(ws + off); off += (size_t)NN * CC * 2;
    u16* wfrag = (u16*)(ws + off); off += (size_t)288 * 512 * 2;
    ull* statsAcc = (ull*)(ws + off); off += (size_t)768 * 8;

    k_pre<<<2337, 256, 0, stream>>>(adj, W1r, W1s, W2r, W2s, W3r, W3s, Wl, x,
                                    nbr, cnt, wfrag, yp1, yp2, yp3, Abraw, statsAcc);
    // layer 1 (agg fused in k_pre; root staged from f32 x; no BN on inputs)
    k_gemm<1><<<256, 512, 0, stream>>>(Abraw, x, nullptr, cnt, wfrag, b1,
                                       nullptr, nullptr, nullptr, statsAcc, yp1);
    // layer 2
    k_agg<<<2048, 256, 0, stream>>>(yp1, nbr, cnt, Abraw);
    k_gemm<2><<<256, 512, 0, stream>>>(Abraw, nullptr, yp1, cnt, wfrag + 64 * 512, b2,
                                       statsAcc, g1, be1, statsAcc + 256, yp2);
    // layer 3
    k_agg<<<2048, 256, 0, stream>>>(yp2, nbr, cnt, Abraw);
    k_gemm<3><<<256, 512, 0, stream>>>(Abraw, nullptr, yp2, cnt, wfrag + 128 * 512, b3,
                                       statsAcc + 256, g2, be2, statsAcc + 512, yp3);
    // fused outputs (coefs recomputed per block from int64 stats)
    k_out<<<4096, 256, 0, stream>>>(yp1, yp2, yp3, statsAcc,
                                    g1, be1, g2, be2, g3, be3,
                                    wfrag + 192 * 512, bl, teams, slen, att,
                                    s_out, xcat, oT, oS, oR);
}

// Round 10
// 129.527 us; speedup vs baseline: 1.0144x; 1.0144x over previous
//
#include <hip/hip_runtime.h>
#include <stdint.h>

#define NN 8192
#define CC 128
#define TT 512
#define LL 30
#define CAP 64

typedef unsigned int uint32;
typedef unsigned long long ull;
typedef unsigned short u16;

typedef float f32x4 __attribute__((ext_vector_type(4)));
typedef short bf16x8 __attribute__((ext_vector_type(8)));

#define STAT_SCALE 1048576.0f
#define STAT_INV (1.0f / 1048576.0f)

__device__ __forceinline__ float bf2f(uint32 h) { return __uint_as_float(h << 16); }
__device__ __forceinline__ u16 f2bf(float f) {
    uint32 u = __float_as_uint(f);
    u = (u + 0x7fffu + ((u >> 16) & 1u)) >> 16;
    return (u16)u;
}
__device__ __forceinline__ uint32 pack2(float a, float b) {
    return (uint32)f2bf(a) | ((uint32)f2bf(b) << 16);
}
// coef from int64 stats: a = g*rsqrt(var+eps), b = be - mu*a
__device__ __forceinline__ void coef_from_stats(const ull* __restrict__ st, int c,
                                                const float* __restrict__ g,
                                                const float* __restrict__ be,
                                                float& ca, float& cb) {
    float s = (float)(long long)st[c] * STAT_INV;
    float q = (float)(long long)st[128 + c] * STAT_INV;
    float mu = s * (1.f / NN);
    float var = q * (1.f / NN) - mu * mu;
    float rs = rsqrtf(var + 1e-5f);
    ca = g[c] * rs;
    cb = be[c] - mu * ca;
}

// ============ k_pre: adj scan (4x unrolled, deep loads) + layer-1 agg + W pack + init ============
// blocks [0,2048): adj rows (scan + agg1); [2048,2336): wfrag; 2336: init
__global__ __launch_bounds__(256) void k_pre(
    const float* __restrict__ adj,
    const float* __restrict__ W1r, const float* __restrict__ W1s,
    const float* __restrict__ W2r, const float* __restrict__ W2s,
    const float* __restrict__ W3r, const float* __restrict__ W3s,
    const float* __restrict__ Wl, const float* __restrict__ x0,
    int* __restrict__ nbr, int* __restrict__ cnt,
    u16* __restrict__ wfrag,
    u16* __restrict__ yp1, u16* __restrict__ yp2, u16* __restrict__ yp3,
    u16* __restrict__ Abraw, ull* __restrict__ statsAcc) {
    int b = blockIdx.x, tid = threadIdx.x;
    if (b < 2048) {
        int row = b * 4 + (tid >> 6);
        int lane = tid & 63;
        const float4* arow = (const float4*)(adj + (size_t)row * NN);
        int base = 0;
        int* dst = nbr + (size_t)row * CAP;
        for (int it = 0; it < 32; it += 4) {
            // issue 4 KB of loads per wave before any processing (Little's-law fix)
            float4 v0 = arow[it * 64 + lane];
            float4 v1 = arow[it * 64 + 64 + lane];
            float4 v2 = arow[it * 64 + 128 + lane];
            float4 v3 = arow[it * 64 + 192 + lane];
            float4 vs[4] = {v0, v1, v2, v3};
#pragma unroll
            for (int u = 0; u < 4; ++u) {
                float vv[4] = {vs[u].x, vs[u].y, vs[u].z, vs[u].w};
#pragma unroll
                for (int j = 0; j < 4; ++j) {
                    unsigned long long m = __ballot(vv[j] != 0.f);
                    if (vv[j] != 0.f) {
                        int pos = base + __popcll(m & ((1ull << lane) - 1ull));
                        if (pos < CAP) dst[pos] = (it + u) * 256 + lane * 4 + j;
                    }
                    base += __popcll(m);
                }
            }
        }
        int nn = base < CAP ? base : CAP;
        int npad = (nn + 3) & ~3;
        for (int p = nn + lane; p < npad; p += 64) dst[p] = NN;  // sentinel
        if (lane == 0) cnt[row] = nn;
        // fused layer-1 aggregation straight from f32 x (L2/L3-resident)
        int c = lane * 2;
        float a0 = 0.f, a1 = 0.f;
        for (int j = 0; j < npad; j += 4) {
            int4 m = *(const int4*)(dst + j);
            if (m.x < NN) { float2 v = *(const float2*)(x0 + (size_t)m.x * CC + c); a0 += v.x; a1 += v.y; }
            if (m.y < NN) { float2 v = *(const float2*)(x0 + (size_t)m.y * CC + c); a0 += v.x; a1 += v.y; }
            if (m.z < NN) { float2 v = *(const float2*)(x0 + (size_t)m.z * CC + c); a0 += v.x; a1 += v.y; }
            if (m.w < NN) { float2 v = *(const float2*)(x0 + (size_t)m.w * CC + c); a0 += v.x; a1 += v.y; }
        }
        *(uint32*)(Abraw + (size_t)row * CC + c) = pack2(a0, a1);
    } else if (b < 2336) {
        int bb = b - 2048;
        const float* Wa;
        const float* Wb;
        int tile, gbase;
        if (bb < 64)       { Wa = W1r; Wb = W1s; tile = bb;       gbase = 0; }
        else if (bb < 128) { Wa = W2r; Wb = W2s; tile = bb - 64;  gbase = 64; }
        else if (bb < 192) { Wa = W3r; Wb = W3s; tile = bb - 128; gbase = 128; }
        else               { Wa = Wl;  Wb = nullptr; tile = bb - 192; gbase = 192; }
        int kt = tile >> 3, nt = tile & 7;
        int lane = tid & 63, i0 = (tid >> 6) * 2;
        int n = nt * 16 + (lane & 15);
        u16* dst = wfrag + ((size_t)(gbase + tile) * 64 + lane) * 8;
#pragma unroll
        for (int ii = 0; ii < 2; ++ii) {
            int i = i0 + ii;
            int k = kt * 32 + ((lane >> 4) * 8) + i;
            float v;
            if (Wb) v = (k < 128) ? Wa[k * CC + n] : Wb[(k - 128) * CC + n];
            else    v = Wa[k * CC + n];
            dst[i] = f2bf(v);
        }
    } else {
        if (tid < 128) {
            yp1[(size_t)NN * CC + tid] = 0;   // sentinel zero rows
            yp2[(size_t)NN * CC + tid] = 0;
            yp3[(size_t)NN * CC + tid] = 0;
#pragma unroll
            for (int l = 0; l < 3; ++l) {     // zero int64 stats accumulators
                statsAcc[l * 256 + tid] = 0ull;
                statsAcc[l * 256 + 128 + tid] = 0ull;
            }
        }
    }
}

// ============ k_agg: Abraw[row] = sum_nbr(src) (raw bf16) ============
__global__ __launch_bounds__(256) void k_agg(const u16* __restrict__ src,
                                             const int* __restrict__ nbr,
                                             const int* __restrict__ cnt,
                                             u16* __restrict__ Abraw) {
    int row = blockIdx.x * 4 + (threadIdx.x >> 6);
    int lane = threadIdx.x & 63;
    int c = lane * 2;
    int nreal = cnt[row];
    int npad = (nreal + 3) & ~3;
    const int* nb = nbr + (size_t)row * CAP;
    float a0 = 0.f, a1 = 0.f;
    for (int j = 0; j < npad; j += 4) {
        int4 m = *(const int4*)(nb + j);
        uint32 v0 = *(const uint32*)(src + (size_t)m.x * CC + c);
        uint32 v1 = *(const uint32*)(src + (size_t)m.y * CC + c);
        uint32 v2 = *(const uint32*)(src + (size_t)m.z * CC + c);
        uint32 v3 = *(const uint32*)(src + (size_t)m.w * CC + c);
        a0 += bf2f(v0 & 0xffffu); a1 += bf2f(v0 >> 16);
        a0 += bf2f(v1 & 0xffffu); a1 += bf2f(v1 >> 16);
        a0 += bf2f(v2 & 0xffffu); a1 += bf2f(v2 >> 16);
        a0 += bf2f(v3 & 0xffffu); a1 += bf2f(v3 >> 16);
    }
    *(uint32*)(Abraw + (size_t)row * CC + c) = pack2(a0, a1);
}

// ============ k_gemm<LAYER>: stage A, yp = relu(A@[Wr;Ws]+bias), int64 stats atomics ============
// 256 blocks x 512 threads (8 waves): wave w -> rows (w>>2)*16, cols (w&3)*32. (R5 geometry)
template <int LAYER>
__global__ __launch_bounds__(512) void k_gemm(const u16* __restrict__ Abraw,
                                              const float* __restrict__ x0,
                                              const u16* __restrict__ yprev,
                                              const int* __restrict__ cnt,
                                              const u16* __restrict__ wfrag,
                                              const float* __restrict__ bias,
                                              const ull* __restrict__ statsPrev,
                                              const float* __restrict__ g,
                                              const float* __restrict__ be,
                                              ull* __restrict__ statsOut,
                                              u16* __restrict__ yp) {
    __shared__ u16 A[32][264];  // +8 pad
    __shared__ float sSum[CC], sSq[CC];
    __shared__ alignas(16) float cA[CC];
    __shared__ alignas(16) float cB[CC];
    int tid = threadIdx.x, lane = tid & 63, wid = tid >> 6;
    int row0 = blockIdx.x * 32;
    if (tid < CC) {
        sSum[tid] = 0.f; sSq[tid] = 0.f;
        if constexpr (LAYER > 1) {
            float a, b;
            coef_from_stats(statsPrev, tid, g, be, a, b);
            cA[tid] = a; cB[tid] = b;
        }
    }
    __syncthreads();
    for (int i = tid; i < 1024; i += 512) {
        int r = i >> 5, k = (i & 31) * 8;
        int row = row0 + r;
        uint4 o;
        if constexpr (LAYER == 1) {
            if (k < 128) {
                o = *(const uint4*)(Abraw + (size_t)row * CC + k);
            } else {
                int c = k - 128;
                float4 v0 = *(const float4*)(x0 + (size_t)row * CC + c);
                float4 v1 = *(const float4*)(x0 + (size_t)row * CC + c + 4);
                o.x = pack2(v0.x, v0.y); o.y = pack2(v0.z, v0.w);
                o.z = pack2(v1.x, v1.y); o.w = pack2(v1.z, v1.w);
            }
        } else {
            uint4 raw;
            float fn;
            int c;
            if (k < 128) {
                c = k;
                raw = *(const uint4*)(Abraw + (size_t)row * CC + k);
                fn = (float)cnt[row];
            } else {
                c = k - 128;
                raw = *(const uint4*)(yprev + (size_t)row * CC + c);
                fn = 1.f;
            }
            float4 a0 = *(const float4*)(cA + c);
            float4 a1 = *(const float4*)(cA + c + 4);
            float4 b0 = *(const float4*)(cB + c);
            float4 b1 = *(const float4*)(cB + c + 4);
            o.x = pack2(a0.x * bf2f(raw.x & 0xffffu) + b0.x * fn, a0.y * bf2f(raw.x >> 16) + b0.y * fn);
            o.y = pack2(a0.z * bf2f(raw.y & 0xffffu) + b0.z * fn, a0.w * bf2f(raw.y >> 16) + b0.w * fn);
            o.z = pack2(a1.x * bf2f(raw.z & 0xffffu) + b1.x * fn, a1.y * bf2f(raw.z >> 16) + b1.y * fn);
            o.w = pack2(a1.z * bf2f(raw.w & 0xffffu) + b1.z * fn, a1.w * bf2f(raw.w >> 16) + b1.w * fn);
        }
        *(uint4*)&A[r][k] = o;
    }
    __syncthreads();

    int mh = wid >> 2, nh = wid & 3;
    int arow = mh * 16 + (lane & 15);
    int kg = (lane >> 4) * 8;
    f32x4 acc[2];
#pragma unroll
    for (int nt = 0; nt < 2; ++nt) acc[nt] = (f32x4){0.f, 0.f, 0.f, 0.f};
#pragma unroll
    for (int kt = 0; kt < 8; ++kt) {
        bf16x8 a = *(const bf16x8*)&A[arow][kt * 32 + kg];
        const u16* wb = wfrag + ((size_t)(kt * 8 + nh * 2) * 64 + lane) * 8;
#pragma unroll
        for (int nt = 0; nt < 2; ++nt) {
            bf16x8 bfr = *(const bf16x8*)(wb + (size_t)nt * 512);
            acc[nt] = __builtin_amdgcn_mfma_f32_16x16x32_bf16(a, bfr, acc[nt], 0, 0, 0);
        }
    }
    int rowb = row0 + mh * 16 + ((lane >> 4) * 4);
#pragma unroll
    for (int nt = 0; nt < 2; ++nt) {
        int col = nh * 32 + nt * 16 + (lane & 15);
        float bv = bias[col];
        float s1 = 0.f, s2 = 0.f;
#pragma unroll
        for (int q = 0; q < 4; ++q) {
            float y = acc[nt][q] + bv;
            y = y > 0.f ? y : 0.f;
            yp[(size_t)(rowb + q) * CC + col] = f2bf(y);
            s1 += y;
            s2 += y * y;
        }
        s1 += __shfl_xor(s1, 16); s1 += __shfl_xor(s1, 32);
        s2 += __shfl_xor(s2, 16); s2 += __shfl_xor(s2, 32);
        if ((lane >> 4) == 0) { atomicAdd(&sSum[col], s1); atomicAdd(&sSq[col], s2); }
    }
    __syncthreads();
    // int64 fixed-point global accumulation: exact, commutative, deterministic
    if (tid < 128) {
        atomicAdd(statsOut + tid, (ull)(long long)llrintf(sSum[tid] * STAT_SCALE));
    } else if (tid < 256) {
        atomicAdd(statsOut + tid, (ull)(long long)llrintf(sSq[tid - 128] * STAT_SCALE));
    }
}

// ============ k_out: s-GEMM [0,512) + team [512,1024) + xcat normalize [1024,4096) ============
__global__ __launch_bounds__(256) void k_out(
    const u16* __restrict__ yp1, const u16* __restrict__ yp2, const u16* __restrict__ yp3,
    const ull* __restrict__ statsAcc,  // [3][256]
    const float* __restrict__ g1, const float* __restrict__ be1,
    const float* __restrict__ g2, const float* __restrict__ be2,
    const float* __restrict__ g3, const float* __restrict__ be3,
    const u16* __restrict__ wfL, const float* __restrict__ bias,
    const int* __restrict__ teams, const int* __restrict__ slen_p,
    const float* __restrict__ att,
    float* __restrict__ sout, float* __restrict__ xcat,
    float* __restrict__ oT, float* __restrict__ oS, float* __restrict__ oR) {
    __shared__ alignas(16) char pool[12544];   // s-gemm A tile / team scratch
    __shared__ alignas(16) float cAll[768];    // {a[128],b[128]} x 3 layers
    int b = blockIdx.x, tid = threadIdx.x;
    if (tid < 128) {
        const float* gs[3] = {g1, g2, g3};
        const float* bes[3] = {be1, be2, be3};
#pragma unroll
        for (int l = 0; l < 3; ++l) {
            float a, bb;
            coef_from_stats(statsAcc + l * 256, tid, gs[l], bes[l], a, bb);
            cAll[l * 256 + tid] = a;
            cAll[l * 256 + 128 + tid] = bb;
        }
    }
    __syncthreads();
    const u16* yps[3] = {yp1, yp2, yp3};
    if (b < 512) {
        u16 (*A)[392] = (u16(*)[392])pool;  // 16 x 392 = 12544B
        int lane = tid & 63, wid = tid >> 6;
        int row0 = b * 16;
        for (int i = tid; i < 768; i += 256) {
            int r = i / 48, kk = (i % 48) * 8;
            int seg = kk >> 7, c = kk & 127;
            uint4 raw = *(const uint4*)(yps[seg] + (size_t)(row0 + r) * CC + c);
            const float* cf = cAll + seg * 256;
            float4 av0 = *(const float4*)(cf + c);
            float4 av1 = *(const float4*)(cf + c + 4);
            float4 bv0 = *(const float4*)(cf + 128 + c);
            float4 bv1 = *(const float4*)(cf + 128 + c + 4);
            uint4 o;
            o.x = pack2(av0.x * bf2f(raw.x & 0xffffu) + bv0.x, av0.y * bf2f(raw.x >> 16) + bv0.y);
            o.y = pack2(av0.z * bf2f(raw.y & 0xffffu) + bv0.z, av0.w * bf2f(raw.y >> 16) + bv0.w);
            o.z = pack2(av1.x * bf2f(raw.z & 0xffffu) + bv1.x, av1.y * bf2f(raw.z >> 16) + bv1.y);
            o.w = pack2(av1.z * bf2f(raw.w & 0xffffu) + bv1.z, av1.w * bf2f(raw.w >> 16) + bv1.w);
            *(uint4*)&A[r][kk] = o;
        }
        __syncthreads();
        int nh = wid;
        int arow = lane & 15;
        int kg = (lane >> 4) * 8;
        f32x4 acc[2];
#pragma unroll
        for (int nt = 0; nt < 2; ++nt) acc[nt] = (f32x4){0.f, 0.f, 0.f, 0.f};
#pragma unroll
        for (int kt = 0; kt < 12; ++kt) {
            bf16x8 a = *(const bf16x8*)&A[arow][kt * 32 + kg];
            const u16* wb = wfL + ((size_t)(kt * 8 + nh * 2) * 64 + lane) * 8;
#pragma unroll
            for (int nt = 0; nt < 2; ++nt) {
                bf16x8 bfr = *(const bf16x8*)(wb + (size_t)nt * 512);
                acc[nt] = __builtin_amdgcn_mfma_f32_16x16x32_bf16(a, bfr, acc[nt], 0, 0, 0);
            }
        }
        int rowb = row0 + ((lane >> 4) * 4);
#pragma unroll
        for (int nt = 0; nt < 2; ++nt) {
            int col = nh * 32 + nt * 16 + (lane & 15);
            float bv = bias[col];
#pragma unroll
            for (int q = 0; q < 4; ++q) {
                float y = acc[nt][q] + bv;
                sout[(size_t)(rowb + q) * CC + col] = y > 0.f ? y : 0.f;
            }
        }
    } else if (b < 1024) {
        float* wT = (float*)pool;
        float* wS = wT + 32;
        float* wR = wS + 32;
        int* ids = (int*)(wR + 32);
        int t = b - 512;
        if (tid < 64) {
            int lane = tid;
            bool act = lane < LL;
            float a = act ? att[t * LL + lane] : 0.f;
            int id = act ? teams[t * LL + lane] : NN;
            if (act) ids[lane] = id;
            int sl = *slen_p;
            const float NEG = -1e30f;
            float v = act ? a : NEG;
#pragma unroll
            for (int o = 32; o > 0; o >>= 1) v = fmaxf(v, __shfl_xor(v, o));
            float mT = v;
            float eT = act ? __expf(a - mT) : 0.f;
            v = eT;
#pragma unroll
            for (int o = 32; o > 0; o >>= 1) v += __shfl_xor(v, o);
            float sT = v;
            bool inS = act && (lane < sl);
            v = inS ? a : NEG;
#pragma unroll
            for (int o = 32; o > 0; o >>= 1) v = fmaxf(v, __shfl_xor(v, o));
            float mS = v;
            float eS = inS ? __expf(a - mS) : 0.f;
            v = eS;
#pragma unroll
            for (int o = 32; o > 0; o >>= 1) v += __shfl_xor(v, o);
            float sS = v;
            bool inR = act && (lane >= sl) && (id != NN);
            v = inR ? a : NEG;
#pragma unroll
            for (int o = 32; o > 0; o >>= 1) v = fmaxf(v, __shfl_xor(v, o));
            float mR = v;
            float eR = inR ? __expf(a - mR) : 0.f;
            v = eR;
#pragma unroll
            for (int o = 32; o > 0; o >>= 1) v += __shfl_xor(v, o);
            float sR = v;
            if (act) {
                wT[lane] = eT / sT;
                wS[lane] = eS / sS;
                wR[lane] = eR / sR;
            }
        }
        __syncthreads();
        for (int d = tid; d < 384; d += 256) {
            int seg = d >> 7, c = d & 127;
            const u16* xb = yps[seg];
            float ca = cAll[seg * 256 + c];
            float cb = cAll[seg * 256 + 128 + c];
            float aT = 0.f, aS = 0.f, aR = 0.f;
            for (int l = 0; l < LL; ++l) {
                int id = ids[l];
                if (id < NN) {
                    float vv = ca * bf2f((uint32)xb[(size_t)id * CC + c]) + cb;
                    aT += wT[l] * vv;
                    aS += wS[l] * vv;
                    aR += wR[l] * vv;
                }
            }
            oT[(size_t)t * 384 + d] = aT;
            oS[(size_t)t * 384 + d] = aS;
            oR[(size_t)t * 384 + d] = aR;
        }
    } else {
        int idx = (b - 1024) * 256 + tid;  // one per 4 f32
        int n = idx / 96;
        int k = (idx % 96) * 4;
        int seg = k >> 7, c = k & 127;
        ushort4 raw = *(const ushort4*)(yps[seg] + (size_t)n * CC + c);
        const float* cf = cAll + seg * 256;
        float4 a = *(const float4*)(cf + c);
        float4 bb = *(const float4*)(cf + 128 + c);
        float4 o;
        o.x = a.x * bf2f((uint32)raw.x) + bb.x;
        o.y = a.y * bf2f((uint32)raw.y) + bb.y;
        o.z = a.z * bf2f((uint32)raw.z) + bb.z;
        o.w = a.w * bf2f((uint32)raw.w) + bb.w;
        *(float4*)(xcat + (size_t)n * 384 + k) = o;
    }
}

extern "C" void kernel_launch(void* const* d_in, const int* in_sizes, int n_in,
                              void* d_out, int out_size, void* d_ws, size_t ws_size,
                              hipStream_t stream) {
    const float* x = (const float*)d_in[0];
    const float* adj = (const float*)d_in[1];
    const int* teams = (const int*)d_in[2];
    const int* slen = (const int*)d_in[3];
    const float* W1r = (const float*)d_in[4];
    const float* b1 = (const float*)d_in[5];
    const float* W1s = (const float*)d_in[6];
    const float* W2r = (const float*)d_in[7];
    const float* b2 = (const float*)d_in[8];
    const float* W2s = (const float*)d_in[9];
    const float* W3r = (const float*)d_in[10];
    const float* b3 = (const float*)d_in[11];
    const float* W3s = (const float*)d_in[12];
    const float* g1 = (const float*)d_in[13];
    const float* be1 = (const float*)d_in[14];
    const float* g2 = (const float*)d_in[15];
    const float* be2 = (const float*)d_in[16];
    const float* g3 = (const float*)d_in[17];
    const float* be3 = (const float*)d_in[18];
    const float* Wl = (const float*)d_in[19];
    const float* bl = (const float*)d_in[20];
    const float* att = (const float*)d_in[21];

    float* out = (float*)d_out;
    float* s_out = out;
    float* xcat = out + (size_t)NN * CC;
    float* oT = xcat + (size_t)NN * 384;
    float* oS = oT + (size_t)TT * 384;
    float* oR = oS + (size_t)TT * 384;

    char* ws = (char*)d_ws;
    size_t off = 0;
    int* nbr = (int*)(ws + off); off += (size_t)NN * CAP * 4;
    int* cnt = (int*)(ws + off); off += (size_t)NN * 4;
    u16* yp1 = (u16*)(ws + off); off += (size_t)(NN + 1) * CC * 2;
    u16* yp2 = (u16*)(ws + off); off += (size_t)(NN + 1) * CC * 2;
    u16* yp3 = (u16*)(ws + off); off += (size_t)(NN + 1) * CC * 2;
    u16* Abraw = (u16*)(ws + off); off += (size_t)NN * CC * 2;
    u16* wfrag = (u16*)(ws + off); off += (size_t)288 * 512 * 2;
    ull* statsAcc = (ull*)(ws + off); off += (size_t)768 * 8;

    k_pre<<<2337, 256, 0, stream>>>(adj, W1r, W1s, W2r, W2s, W3r, W3s, Wl, x,
                                    nbr, cnt, wfrag, yp1, yp2, yp3, Abraw, statsAcc);
    // layer 1 (agg fused in k_pre; root staged from f32 x; no BN on inputs)
    k_gemm<1><<<256, 512, 0, stream>>>(Abraw, x, nullptr, cnt, wfrag, b1,
                                       nullptr, nullptr, nullptr, statsAcc, yp1);
    // layer 2
    k_agg<<<2048, 256, 0, stream>>>(yp1, nbr, cnt, Abraw);
    k_gemm<2><<<256, 512, 0, stream>>>(Abraw, nullptr, yp1, cnt, wfrag + 64 * 512, b2,
                                       statsAcc, g1, be1, statsAcc + 256, yp2);
    // layer 3
    k_agg<<<2048, 256, 0, stream>>>(yp2, nbr, cnt, Abraw);
    k_gemm<3><<<256, 512, 0, stream>>>(Abraw, nullptr, yp2, cnt, wfrag + 128 * 512, b3,
                                       statsAcc + 256, g2, be2, statsAcc + 512, yp3);
    // fused outputs (coefs recomputed per block from int64 stats)
    k_out<<<4096, 256, 0, stream>>>(yp1, yp2, yp3, statsAcc,
                                    g1, be1, g2, be2, g3, be3,
                                    wfrag + 192 * 512, bl, teams, slen, att,
                                    s_out, xcat, oT, oS, oR);
}